// Round 1
// baseline (1201.655 us; speedup 1.0000x reference)
//
#include <hip/hip_runtime.h>
#include <cstdint>
#include <cstddef>

#define T_TOK 1024
#define H_DIM 1024
#define E_NUM 16
#define M_DIM 4096
#define GU_DIM 8192
#define ALPHA 1.702f
#define LIMIT 7.0f

// workspace layout (byte offsets)
#define WS_COUNTS   0            // 16 int
#define WS_OFFSETS  256          // 17 int
#define WS_TOKE     512          // 2048 int
#define WS_TOKP     (WS_TOKE + 8192)
#define WS_TOKW     (WS_TOKP + 8192)
#define WS_TOKG     (WS_TOKW + 8192)
#define WS_SLOTTOK  (WS_TOKG + 8192)
#define WS_GATED    65536                        // 2048*4096 f32 = 32 MB
#define WS_OUT      (WS_GATED + 2048*4096*4)     // 2048*1024 f32 = 8 MB

__global__ __launch_bounds__(64) void k_zero(int* counts) {
    if (threadIdx.x < E_NUM) counts[threadIdx.x] = 0;
}

__global__ __launch_bounds__(64) void k_router(
    const float* __restrict__ x, const float* __restrict__ rw, const float* __restrict__ rb,
    float* __restrict__ scores, int* __restrict__ counts,
    int* __restrict__ tok_e, int* __restrict__ tok_p, float* __restrict__ tok_w)
{
    const int t = blockIdx.x;
    const int lane = threadIdx.x;
    float part[E_NUM];
#pragma unroll
    for (int e = 0; e < E_NUM; ++e) part[e] = 0.f;
    const float* xrow = x + (size_t)t * H_DIM;
    for (int h = lane; h < H_DIM; h += 64) {
        float xv = xrow[h];
        const float* wrow = rw + (size_t)h * E_NUM;
#pragma unroll
        for (int e = 0; e < E_NUM; ++e) part[e] = fmaf(xv, wrow[e], part[e]);
    }
    __shared__ float red[64][E_NUM];
    __shared__ float logits[E_NUM];
    __shared__ int se[2];
    __shared__ float sw[2];
#pragma unroll
    for (int e = 0; e < E_NUM; ++e) red[lane][e] = part[e];
    __syncthreads();
    if (lane < E_NUM) {
        float s = rb[lane];
        for (int l = 0; l < 64; ++l) s += red[l][lane];
        logits[lane] = s;
    }
    __syncthreads();
    if (lane == 0) {
        int i0 = 0; float v0 = logits[0];
        for (int e = 1; e < E_NUM; ++e) { float v = logits[e]; if (v > v0) { v0 = v; i0 = e; } }
        int i1 = -1; float v1 = -3.4e38f;
        for (int e = 0; e < E_NUM; ++e) {
            if (e == i0) continue;
            float v = logits[e];
            if (v > v1) { v1 = v; i1 = e; }
        }
        float ex = expf(v1 - v0);          // <= 1, stable
        float w0 = 1.f / (1.f + ex);
        float w1 = ex / (1.f + ex);
        int p0 = atomicAdd(&counts[i0], 1);
        int p1 = atomicAdd(&counts[i1], 1);
        tok_e[2*t]   = i0; tok_p[2*t]   = p0; tok_w[2*t]   = w0;
        tok_e[2*t+1] = i1; tok_p[2*t+1] = p1; tok_w[2*t+1] = w1;
        se[0] = i0; se[1] = i1; sw[0] = w0; sw[1] = w1;
    }
    __syncthreads();
    if (lane < E_NUM) {
        float v = 0.f;
        if (lane == se[0]) v = sw[0];
        else if (lane == se[1]) v = sw[1];
        scores[(size_t)t * E_NUM + lane] = v;
    }
}

__global__ __launch_bounds__(64) void k_offsets(const int* __restrict__ counts, int* __restrict__ offsets) {
    if (threadIdx.x == 0) {
        int acc = 0;
        for (int e = 0; e < E_NUM; ++e) { offsets[e] = acc; acc += counts[e]; }
        offsets[E_NUM] = acc;
    }
}

__global__ __launch_bounds__(256) void k_build(
    const int* __restrict__ tok_e, const int* __restrict__ tok_p, const int* __restrict__ offsets,
    int* __restrict__ tok_g, int* __restrict__ slot_tok)
{
    int i = blockIdx.x * blockDim.x + threadIdx.x;
    if (i >= 2 * T_TOK) return;
    int e = tok_e[i], p = tok_p[i];
    int g = offsets[e] + p;
    tok_g[i] = g;
    slot_tok[g] = i >> 1;
}

// gate_up GEMM: rows = expert slots (gathered tokens), cols = 64 of 8192 gate_up cols.
// Epilogue: pair (even,odd) cols -> clip -> GLU -> gated[slot][m]
__global__ __launch_bounds__(256) void k_gateup(
    const float* __restrict__ x, const float* __restrict__ W, const float* __restrict__ bias,
    const int* __restrict__ counts, const int* __restrict__ offsets,
    const int* __restrict__ slot_tok, float* __restrict__ gated)
{
    const int e = blockIdx.z;
    const int cnt = counts[e];
    const int row0 = blockIdx.y * 64;
    if (row0 >= cnt) return;
    const int c0 = blockIdx.x * 64;
    const int off = offsets[e];
    __shared__ float As[16][68];
    __shared__ float Bs[16][68];
    const int tid = threadIdx.x;
    const int arow = tid >> 2;
    const int ak = (tid & 3) << 2;
    int r = row0 + arow;
    const int atok = slot_tok[off + (r < cnt ? r : 0)];
    const float* aptr = x + (size_t)atok * H_DIM + ak;
    const int bk = tid >> 4;
    const int bc = (tid & 15) << 2;
    const float* bptr = W + (size_t)e * H_DIM * GU_DIM + (size_t)bk * GU_DIM + c0 + bc;
    float acc[4][4];
#pragma unroll
    for (int i = 0; i < 4; ++i)
#pragma unroll
        for (int j = 0; j < 4; ++j) acc[i][j] = 0.f;
    const int tx = tid & 15, ty = tid >> 4;
    for (int k0 = 0; k0 < H_DIM; k0 += 16) {
        float4 av = *(const float4*)(aptr + k0);
        float4 bv = *(const float4*)(bptr + (size_t)k0 * GU_DIM);
        As[ak+0][arow] = av.x; As[ak+1][arow] = av.y; As[ak+2][arow] = av.z; As[ak+3][arow] = av.w;
        Bs[bk][bc+0] = bv.x;   Bs[bk][bc+1] = bv.y;   Bs[bk][bc+2] = bv.z;   Bs[bk][bc+3] = bv.w;
        __syncthreads();
#pragma unroll
        for (int k = 0; k < 16; ++k) {
            float a0 = As[k][ty*4+0], a1 = As[k][ty*4+1], a2 = As[k][ty*4+2], a3 = As[k][ty*4+3];
            float b0 = Bs[k][tx*4+0], b1 = Bs[k][tx*4+1], b2 = Bs[k][tx*4+2], b3 = Bs[k][tx*4+3];
            acc[0][0] = fmaf(a0,b0,acc[0][0]); acc[0][1] = fmaf(a0,b1,acc[0][1]);
            acc[0][2] = fmaf(a0,b2,acc[0][2]); acc[0][3] = fmaf(a0,b3,acc[0][3]);
            acc[1][0] = fmaf(a1,b0,acc[1][0]); acc[1][1] = fmaf(a1,b1,acc[1][1]);
            acc[1][2] = fmaf(a1,b2,acc[1][2]); acc[1][3] = fmaf(a1,b3,acc[1][3]);
            acc[2][0] = fmaf(a2,b0,acc[2][0]); acc[2][1] = fmaf(a2,b1,acc[2][1]);
            acc[2][2] = fmaf(a2,b2,acc[2][2]); acc[2][3] = fmaf(a2,b3,acc[2][3]);
            acc[3][0] = fmaf(a3,b0,acc[3][0]); acc[3][1] = fmaf(a3,b1,acc[3][1]);
            acc[3][2] = fmaf(a3,b2,acc[3][2]); acc[3][3] = fmaf(a3,b3,acc[3][3]);
        }
        __syncthreads();
    }
    const float* brow = bias + (size_t)e * GU_DIM + c0;
#pragma unroll
    for (int i = 0; i < 4; ++i) {
        int rr = row0 + ty*4 + i;
        if (rr >= cnt) continue;
        size_t gbase = (size_t)(off + rr) * M_DIM + (c0 >> 1);
#pragma unroll
        for (int p = 0; p < 2; ++p) {
            float g = acc[i][2*p]   + brow[tx*4 + 2*p];
            float u = acc[i][2*p+1] + brow[tx*4 + 2*p + 1];
            g = fminf(g, LIMIT);
            g = fmaxf(g, -1e9f);
            u = fminf(fmaxf(u, -LIMIT), LIMIT);
            float glu = g / (1.0f + expf(-ALPHA * g));   // g * sigmoid(alpha*g)
            gated[gbase + tx*2 + p] = (u + 1.0f) * glu;
        }
    }
}

// down GEMM: rows = expert slots (contiguous gated rows), cols = 64 of 1024 h
__global__ __launch_bounds__(256) void k_down(
    const float* __restrict__ gated, const float* __restrict__ W,
    const int* __restrict__ counts, const int* __restrict__ offsets,
    float* __restrict__ outws)
{
    const int e = blockIdx.z;
    const int cnt = counts[e];
    const int row0 = blockIdx.y * 64;
    if (row0 >= cnt) return;
    const int c0 = blockIdx.x * 64;
    const int off = offsets[e];
    __shared__ float As[16][68];
    __shared__ float Bs[16][68];
    const int tid = threadIdx.x;
    const int arow = tid >> 2;
    const int ak = (tid & 3) << 2;
    int r = row0 + arow; if (r >= cnt) r = 0;
    const float* aptr = gated + (size_t)(off + r) * M_DIM + ak;
    const int bk = tid >> 4;
    const int bc = (tid & 15) << 2;
    const float* bptr = W + (size_t)e * M_DIM * H_DIM + (size_t)bk * H_DIM + c0 + bc;
    float acc[4][4];
#pragma unroll
    for (int i = 0; i < 4; ++i)
#pragma unroll
        for (int j = 0; j < 4; ++j) acc[i][j] = 0.f;
    const int tx = tid & 15, ty = tid >> 4;
    for (int k0 = 0; k0 < M_DIM; k0 += 16) {
        float4 av = *(const float4*)(aptr + k0);
        float4 bv = *(const float4*)(bptr + (size_t)k0 * H_DIM);
        As[ak+0][arow] = av.x; As[ak+1][arow] = av.y; As[ak+2][arow] = av.z; As[ak+3][arow] = av.w;
        Bs[bk][bc+0] = bv.x;   Bs[bk][bc+1] = bv.y;   Bs[bk][bc+2] = bv.z;   Bs[bk][bc+3] = bv.w;
        __syncthreads();
#pragma unroll
        for (int k = 0; k < 16; ++k) {
            float a0 = As[k][ty*4+0], a1 = As[k][ty*4+1], a2 = As[k][ty*4+2], a3 = As[k][ty*4+3];
            float b0 = Bs[k][tx*4+0], b1 = Bs[k][tx*4+1], b2 = Bs[k][tx*4+2], b3 = Bs[k][tx*4+3];
            acc[0][0] = fmaf(a0,b0,acc[0][0]); acc[0][1] = fmaf(a0,b1,acc[0][1]);
            acc[0][2] = fmaf(a0,b2,acc[0][2]); acc[0][3] = fmaf(a0,b3,acc[0][3]);
            acc[1][0] = fmaf(a1,b0,acc[1][0]); acc[1][1] = fmaf(a1,b1,acc[1][1]);
            acc[1][2] = fmaf(a1,b2,acc[1][2]); acc[1][3] = fmaf(a1,b3,acc[1][3]);
            acc[2][0] = fmaf(a2,b0,acc[2][0]); acc[2][1] = fmaf(a2,b1,acc[2][1]);
            acc[2][2] = fmaf(a2,b2,acc[2][2]); acc[2][3] = fmaf(a2,b3,acc[2][3]);
            acc[3][0] = fmaf(a3,b0,acc[3][0]); acc[3][1] = fmaf(a3,b1,acc[3][1]);
            acc[3][2] = fmaf(a3,b2,acc[3][2]); acc[3][3] = fmaf(a3,b3,acc[3][3]);
        }
        __syncthreads();
    }
#pragma unroll
    for (int i = 0; i < 4; ++i) {
        int rr = row0 + ty*4 + i;
        if (rr >= cnt) continue;
        float4 v;
        v.x = acc[i][0]; v.y = acc[i][1]; v.z = acc[i][2]; v.w = acc[i][3];
        *(float4*)(outws + (size_t)(off + rr) * H_DIM + c0 + tx*4) = v;
    }
}

__global__ __launch_bounds__(256) void k_final(
    const float* __restrict__ outws, const float* __restrict__ db,
    const int* __restrict__ tok_e, const int* __restrict__ tok_g, const float* __restrict__ tok_w,
    float* __restrict__ out)
{
    const int t = blockIdx.x;
    const int tid = threadIdx.x;
    const int h = tid << 2;
    const int e0 = tok_e[2*t], e1 = tok_e[2*t+1];
    const int g0 = tok_g[2*t], g1 = tok_g[2*t+1];
    const float w0 = tok_w[2*t], w1 = tok_w[2*t+1];
    float4 o0 = *(const float4*)(outws + (size_t)g0 * H_DIM + h);
    float4 o1 = *(const float4*)(outws + (size_t)g1 * H_DIM + h);
    float4 b0 = *(const float4*)(db + (size_t)e0 * H_DIM + h);
    float4 b1 = *(const float4*)(db + (size_t)e1 * H_DIM + h);
    float4 r;
    r.x = w0 * (o0.x + b0.x) + w1 * (o1.x + b1.x);
    r.y = w0 * (o0.y + b0.y) + w1 * (o1.y + b1.y);
    r.z = w0 * (o0.z + b0.z) + w1 * (o1.z + b1.z);
    r.w = w0 * (o0.w + b0.w) + w1 * (o1.w + b1.w);
    *(float4*)(out + (size_t)t * H_DIM + h) = r;
}

extern "C" void kernel_launch(void* const* d_in, const int* in_sizes, int n_in,
                              void* d_out, int out_size, void* d_ws, size_t ws_size,
                              hipStream_t stream) {
    const float* x     = (const float*)d_in[0];
    const float* rw    = (const float*)d_in[1];
    const float* rb    = (const float*)d_in[2];
    const float* gup   = (const float*)d_in[3];
    const float* gup_b = (const float*)d_in[4];
    const float* dw    = (const float*)d_in[5];
    const float* db    = (const float*)d_in[6];
    float* out    = (float*)d_out;                       // final: T*H
    float* scores = out + (size_t)T_TOK * H_DIM;         // router_scores: T*E

    char* ws = (char*)d_ws;
    int*   counts   = (int*)(ws + WS_COUNTS);
    int*   offsets  = (int*)(ws + WS_OFFSETS);
    int*   tok_e    = (int*)(ws + WS_TOKE);
    int*   tok_p    = (int*)(ws + WS_TOKP);
    float* tok_w    = (float*)(ws + WS_TOKW);
    int*   tok_g    = (int*)(ws + WS_TOKG);
    int*   slot_tok = (int*)(ws + WS_SLOTTOK);
    float* gated    = (float*)(ws + WS_GATED);
    float* outws    = (float*)(ws + WS_OUT);

    k_zero<<<1, 64, 0, stream>>>(counts);
    k_router<<<T_TOK, 64, 0, stream>>>(x, rw, rb, scores, counts, tok_e, tok_p, tok_w);
    k_offsets<<<1, 64, 0, stream>>>(counts, offsets);
    k_build<<<(2*T_TOK + 255)/256, 256, 0, stream>>>(tok_e, tok_p, offsets, tok_g, slot_tok);
    dim3 g2(GU_DIM/64, T_TOK/64, E_NUM);
    k_gateup<<<g2, 256, 0, stream>>>(x, gup, gup_b, counts, offsets, slot_tok, gated);
    dim3 g3(H_DIM/64, T_TOK/64, E_NUM);
    k_down<<<g3, 256, 0, stream>>>(gated, dw, counts, offsets, outws);
    k_final<<<T_TOK, 256, 0, stream>>>(outws, db, tok_e, tok_g, tok_w, out);
}

// Round 2
// 390.463 us; speedup vs baseline: 3.0775x; 3.0775x over previous
//
#include <hip/hip_runtime.h>
#include <hip/hip_bf16.h>
#include <cstdint>
#include <cstddef>

typedef unsigned short u16;
typedef __bf16 v8bf __attribute__((ext_vector_type(8)));
typedef float v4f __attribute__((ext_vector_type(4)));

#define T_TOK 1024
#define H_DIM 1024
#define E_NUM 16
#define M_DIM 4096
#define GU_DIM 8192
#define ALPHA 1.702f
#define LIMIT 7.0f
#define LDSTR 40   // ushorts per LDS row: 32 data + 8 pad = 80 B (5 x 16B slots -> conflict-free)

// workspace layout (byte offsets)
#define WS_COUNTS   0
#define WS_OFFSETS  256
#define WS_TOKE     512
#define WS_TOKP     (WS_TOKE + 8192)
#define WS_TOKW     (WS_TOKP + 8192)
#define WS_TOKG     (WS_TOKW + 8192)
#define WS_SLOTTOK  (WS_TOKG + 8192)
#define WS_XG       65536                                  // 2048*1024 bf16 = 4 MB
#define WS_GATED    (WS_XG + 2048*1024*2)                  // 2048*4096 bf16 = 16 MB
#define WS_OUT      (WS_GATED + (size_t)2048*4096*2)       // 2048*1024 f32 = 8 MB

static __device__ __forceinline__ u16 f2bf(float f) {
    union { __hip_bfloat16 b; u16 u; } cv;
    cv.b = __float2bfloat16(f);
    return cv.u;
}

__global__ __launch_bounds__(64) void k_zero(int* counts) {
    if (threadIdx.x < E_NUM) counts[threadIdx.x] = 0;
}

__global__ __launch_bounds__(64) void k_router(
    const float* __restrict__ x, const float* __restrict__ rw, const float* __restrict__ rb,
    float* __restrict__ scores, int* __restrict__ counts,
    int* __restrict__ tok_e, int* __restrict__ tok_p, float* __restrict__ tok_w)
{
    const int t = blockIdx.x;
    const int lane = threadIdx.x;
    float part[E_NUM];
#pragma unroll
    for (int e = 0; e < E_NUM; ++e) part[e] = 0.f;
    const float* xrow = x + (size_t)t * H_DIM;
    for (int h = lane; h < H_DIM; h += 64) {
        float xv = xrow[h];
        const float* wrow = rw + (size_t)h * E_NUM;
#pragma unroll
        for (int e = 0; e < E_NUM; ++e) part[e] = fmaf(xv, wrow[e], part[e]);
    }
    __shared__ float red[64][E_NUM];
    __shared__ float logits[E_NUM];
    __shared__ int se[2];
    __shared__ float sw[2];
#pragma unroll
    for (int e = 0; e < E_NUM; ++e) red[lane][e] = part[e];
    __syncthreads();
    if (lane < E_NUM) {
        float s = rb[lane];
        for (int l = 0; l < 64; ++l) s += red[l][lane];
        logits[lane] = s;
    }
    __syncthreads();
    if (lane == 0) {
        int i0 = 0; float v0 = logits[0];
        for (int e = 1; e < E_NUM; ++e) { float v = logits[e]; if (v > v0) { v0 = v; i0 = e; } }
        int i1 = -1; float v1 = -3.4e38f;
        for (int e = 0; e < E_NUM; ++e) {
            if (e == i0) continue;
            float v = logits[e];
            if (v > v1) { v1 = v; i1 = e; }
        }
        float ex = expf(v1 - v0);
        float w0 = 1.f / (1.f + ex);
        float w1 = ex / (1.f + ex);
        int p0 = atomicAdd(&counts[i0], 1);
        int p1 = atomicAdd(&counts[i1], 1);
        tok_e[2*t]   = i0; tok_p[2*t]   = p0; tok_w[2*t]   = w0;
        tok_e[2*t+1] = i1; tok_p[2*t+1] = p1; tok_w[2*t+1] = w1;
        se[0] = i0; se[1] = i1; sw[0] = w0; sw[1] = w1;
    }
    __syncthreads();
    if (lane < E_NUM) {
        float v = 0.f;
        if (lane == se[0]) v = sw[0];
        else if (lane == se[1]) v = sw[1];
        scores[(size_t)t * E_NUM + lane] = v;
    }
}

__global__ __launch_bounds__(64) void k_offsets(const int* __restrict__ counts, int* __restrict__ offsets) {
    if (threadIdx.x == 0) {
        int acc = 0;
        for (int e = 0; e < E_NUM; ++e) { offsets[e] = acc; acc += counts[e]; }
        offsets[E_NUM] = acc;
    }
}

__global__ __launch_bounds__(256) void k_build(
    const int* __restrict__ tok_e, const int* __restrict__ tok_p, const int* __restrict__ offsets,
    int* __restrict__ tok_g, int* __restrict__ slot_tok)
{
    int i = blockIdx.x * blockDim.x + threadIdx.x;
    if (i >= 2 * T_TOK) return;
    int e = tok_e[i], p = tok_p[i];
    int g = offsets[e] + p;
    tok_g[i] = g;
    slot_tok[g] = i >> 1;
}

// gather tokens into slot order, f32 -> bf16
__global__ __launch_bounds__(256) void k_gather(
    const float* __restrict__ x, const int* __restrict__ slot_tok, u16* __restrict__ xg)
{
    const int g = blockIdx.x;
    const int t = slot_tok[g];
    const float4* src = (const float4*)(x + (size_t)t * H_DIM);
    float4 v = src[threadIdx.x];
    ushort4 o;
    o.x = f2bf(v.x); o.y = f2bf(v.y); o.z = f2bf(v.z); o.w = f2bf(v.w);
    *(ushort4*)&xg[(size_t)g * H_DIM + threadIdx.x * 4] = o;
}

// ---------------- gate_up MFMA GEMM ----------------
// BM=128 rows (slots), 64 m per block (=128 interleaved W cols), BK=32, 4 waves.
// Each wave: 32 rows x 128 LDS cols. LDS cols 0..63 = gate(m), 64..127 = up(m).
__global__ __launch_bounds__(256) void k_gateup(
    const u16* __restrict__ xg, const float* __restrict__ W, const float* __restrict__ bias,
    const int* __restrict__ counts, const int* __restrict__ offsets,
    u16* __restrict__ gated)
{
    const int e = blockIdx.z;
    const int cnt = counts[e];
    const int row0 = blockIdx.y * 128;
    if (row0 >= cnt) return;
    const int m0 = blockIdx.x * 64;
    const int off = offsets[e];
    __shared__ u16 As[128 * LDSTR];
    __shared__ u16 Bs[128 * LDSTR];
    const int tid = threadIdx.x;
    const int lane = tid & 63;
    const int w = tid >> 6;

    // A staging: 512 16B-chunks (128 rows x 4 segs), 2 per thread
    const int ar0 = tid >> 2, aseg = tid & 3;
    const int ar1 = ar0 + 64;
    int gr0 = row0 + ar0; if (gr0 >= cnt) gr0 = cnt - 1;
    int gr1 = row0 + ar1; if (gr1 >= cnt) gr1 = cnt - 1;
    const u16* aP0 = xg + (size_t)(off + gr0) * H_DIM + aseg * 8;
    const u16* aP1 = xg + (size_t)(off + gr1) * H_DIM + aseg * 8;

    // B staging: 512 strips (128 cols x 4 k-strips of 8), 2 per thread (k and k+16)
    const int bn   = tid & 127;
    const int bk0  = (tid >> 7) * 8;                 // 0 or 8
    const int bcol = (bn >> 1) + (bn & 1) * 64;      // de-interleave: even->gate half, odd->up half
    const float* bP = W + (size_t)e * H_DIM * GU_DIM + (size_t)bk0 * GU_DIM + 2 * m0 + bn;

    uint4 ra0, ra1;
    float rb[16];
    v4f acc0[8], acc1[8];
    v4f zz = {0.f, 0.f, 0.f, 0.f};
#pragma unroll
    for (int f = 0; f < 8; ++f) { acc0[f] = zz; acc1[f] = zz; }

    const u16* aF = &As[(w * 32 + (lane & 15)) * LDSTR + (lane >> 4) * 8];
    const u16* bF = &Bs[(lane & 15) * LDSTR + (lane >> 4) * 8];

#define GU_LOAD(K0)                                                       \
    ra0 = *(const uint4*)(aP0 + (K0));                                    \
    ra1 = *(const uint4*)(aP1 + (K0));                                    \
    _Pragma("unroll")                                                     \
    for (int i = 0; i < 8; ++i) {                                         \
        rb[i]     = bP[(size_t)((K0) + i) * GU_DIM];                      \
        rb[i + 8] = bP[(size_t)((K0) + 16 + i) * GU_DIM];                 \
    }

    GU_LOAD(0)
    for (int kt = 0; kt < H_DIM / 32; ++kt) {
        *(uint4*)&As[ar0 * LDSTR + aseg * 8] = ra0;
        *(uint4*)&As[ar1 * LDSTR + aseg * 8] = ra1;
        uint4 p0, p1;
        p0.x = f2bf(rb[0])  | ((unsigned)f2bf(rb[1])  << 16);
        p0.y = f2bf(rb[2])  | ((unsigned)f2bf(rb[3])  << 16);
        p0.z = f2bf(rb[4])  | ((unsigned)f2bf(rb[5])  << 16);
        p0.w = f2bf(rb[6])  | ((unsigned)f2bf(rb[7])  << 16);
        p1.x = f2bf(rb[8])  | ((unsigned)f2bf(rb[9])  << 16);
        p1.y = f2bf(rb[10]) | ((unsigned)f2bf(rb[11]) << 16);
        p1.z = f2bf(rb[12]) | ((unsigned)f2bf(rb[13]) << 16);
        p1.w = f2bf(rb[14]) | ((unsigned)f2bf(rb[15]) << 16);
        *(uint4*)&Bs[bcol * LDSTR + bk0]      = p0;
        *(uint4*)&Bs[bcol * LDSTR + bk0 + 16] = p1;
        __syncthreads();
        if (kt + 1 < H_DIM / 32) { GU_LOAD((kt + 1) * 32) }
        v8bf a0 = *(const v8bf*)aF;
        v8bf a1 = *(const v8bf*)(aF + 16 * LDSTR);
#pragma unroll
        for (int f = 0; f < 8; ++f) {
            v8bf b = *(const v8bf*)(bF + f * 16 * LDSTR);
            acc0[f] = __builtin_amdgcn_mfma_f32_16x16x32_bf16(a0, b, acc0[f], 0, 0, 0);
            acc1[f] = __builtin_amdgcn_mfma_f32_16x16x32_bf16(a1, b, acc1[f], 0, 0, 0);
        }
        __syncthreads();
    }
#undef GU_LOAD

    const float* bg = bias + (size_t)e * GU_DIM + 2 * m0;
#pragma unroll
    for (int i = 0; i < 2; ++i) {
#pragma unroll
        for (int r = 0; r < 4; ++r) {
            int rr = row0 + w * 32 + i * 16 + (lane >> 4) * 4 + r;
            if (rr >= cnt) continue;
            u16* orow = gated + (size_t)(off + rr) * M_DIM + m0;
#pragma unroll
            for (int f = 0; f < 4; ++f) {
                int ml = f * 16 + (lane & 15);
                float g = (i ? acc1[f][r]     : acc0[f][r])     + bg[2 * ml];
                float u = (i ? acc1[f + 4][r] : acc0[f + 4][r]) + bg[2 * ml + 1];
                g = fminf(g, LIMIT); g = fmaxf(g, -1e9f);
                u = fminf(fmaxf(u, -LIMIT), LIMIT);
                float glu = g / (1.f + expf(-ALPHA * g));
                orow[ml] = f2bf((u + 1.f) * glu);
            }
        }
    }
}

// ---------------- down MFMA GEMM ----------------
// BM=128 rows, BN=64 cols, BK=32, 4 waves (each 32 rows x 64 cols)
__global__ __launch_bounds__(256) void k_down(
    const u16* __restrict__ gated, const float* __restrict__ W,
    const int* __restrict__ counts, const int* __restrict__ offsets,
    float* __restrict__ outws)
{
    const int e = blockIdx.z;
    const int cnt = counts[e];
    const int row0 = blockIdx.y * 128;
    if (row0 >= cnt) return;
    const int c0 = blockIdx.x * 64;
    const int off = offsets[e];
    __shared__ u16 As[128 * LDSTR];
    __shared__ u16 Bs[64 * LDSTR];
    const int tid = threadIdx.x;
    const int lane = tid & 63;
    const int w = tid >> 6;

    const int ar0 = tid >> 2, aseg = tid & 3;
    const int ar1 = ar0 + 64;
    int gr0 = row0 + ar0; if (gr0 >= cnt) gr0 = cnt - 1;
    int gr1 = row0 + ar1; if (gr1 >= cnt) gr1 = cnt - 1;
    const u16* aP0 = gated + (size_t)(off + gr0) * M_DIM + aseg * 8;
    const u16* aP1 = gated + (size_t)(off + gr1) * M_DIM + aseg * 8;

    const int bn  = tid & 63;
    const int bk0 = (tid >> 6) * 8;          // 0,8,16,24
    const float* bP = W + (size_t)e * M_DIM * H_DIM + (size_t)bk0 * H_DIM + c0 + bn;

    uint4 ra0, ra1;
    float rb[8];
    v4f acc0[4], acc1[4];
    v4f zz = {0.f, 0.f, 0.f, 0.f};
#pragma unroll
    for (int f = 0; f < 4; ++f) { acc0[f] = zz; acc1[f] = zz; }

    const u16* aF = &As[(w * 32 + (lane & 15)) * LDSTR + (lane >> 4) * 8];
    const u16* bF = &Bs[(lane & 15) * LDSTR + (lane >> 4) * 8];

#define DN_LOAD(K0)                                                       \
    ra0 = *(const uint4*)(aP0 + (K0));                                    \
    ra1 = *(const uint4*)(aP1 + (K0));                                    \
    _Pragma("unroll")                                                     \
    for (int i = 0; i < 8; ++i) rb[i] = bP[(size_t)((K0) + i) * H_DIM];

    DN_LOAD(0)
    for (int kt = 0; kt < M_DIM / 32; ++kt) {
        *(uint4*)&As[ar0 * LDSTR + aseg * 8] = ra0;
        *(uint4*)&As[ar1 * LDSTR + aseg * 8] = ra1;
        uint4 p0;
        p0.x = f2bf(rb[0]) | ((unsigned)f2bf(rb[1]) << 16);
        p0.y = f2bf(rb[2]) | ((unsigned)f2bf(rb[3]) << 16);
        p0.z = f2bf(rb[4]) | ((unsigned)f2bf(rb[5]) << 16);
        p0.w = f2bf(rb[6]) | ((unsigned)f2bf(rb[7]) << 16);
        *(uint4*)&Bs[bn * LDSTR + bk0] = p0;
        __syncthreads();
        if (kt + 1 < M_DIM / 32) { DN_LOAD((kt + 1) * 32) }
        v8bf a0 = *(const v8bf*)aF;
        v8bf a1 = *(const v8bf*)(aF + 16 * LDSTR);
#pragma unroll
        for (int f = 0; f < 4; ++f) {
            v8bf b = *(const v8bf*)(bF + f * 16 * LDSTR);
            acc0[f] = __builtin_amdgcn_mfma_f32_16x16x32_bf16(a0, b, acc0[f], 0, 0, 0);
            acc1[f] = __builtin_amdgcn_mfma_f32_16x16x32_bf16(a1, b, acc1[f], 0, 0, 0);
        }
        __syncthreads();
    }
#undef DN_LOAD

#pragma unroll
    for (int i = 0; i < 2; ++i) {
#pragma unroll
        for (int r = 0; r < 4; ++r) {
            int rr = row0 + w * 32 + i * 16 + (lane >> 4) * 4 + r;
            if (rr >= cnt) continue;
            float* orow = outws + (size_t)(off + rr) * H_DIM + c0;
#pragma unroll
            for (int f = 0; f < 4; ++f) {
                orow[f * 16 + (lane & 15)] = (i ? acc1[f][r] : acc0[f][r]);
            }
        }
    }
}

__global__ __launch_bounds__(256) void k_final(
    const float* __restrict__ outws, const float* __restrict__ db,
    const int* __restrict__ tok_e, const int* __restrict__ tok_g, const float* __restrict__ tok_w,
    float* __restrict__ out)
{
    const int t = blockIdx.x;
    const int tid = threadIdx.x;
    const int h = tid << 2;
    const int e0 = tok_e[2*t], e1 = tok_e[2*t+1];
    const int g0 = tok_g[2*t], g1 = tok_g[2*t+1];
    const float w0 = tok_w[2*t], w1 = tok_w[2*t+1];
    float4 o0 = *(const float4*)(outws + (size_t)g0 * H_DIM + h);
    float4 o1 = *(const float4*)(outws + (size_t)g1 * H_DIM + h);
    float4 b0 = *(const float4*)(db + (size_t)e0 * H_DIM + h);
    float4 b1 = *(const float4*)(db + (size_t)e1 * H_DIM + h);
    float4 r;
    r.x = w0 * (o0.x + b0.x) + w1 * (o1.x + b1.x);
    r.y = w0 * (o0.y + b0.y) + w1 * (o1.y + b1.y);
    r.z = w0 * (o0.z + b0.z) + w1 * (o1.z + b1.z);
    r.w = w0 * (o0.w + b0.w) + w1 * (o1.w + b1.w);
    *(float4*)(out + (size_t)t * H_DIM + h) = r;
}

extern "C" void kernel_launch(void* const* d_in, const int* in_sizes, int n_in,
                              void* d_out, int out_size, void* d_ws, size_t ws_size,
                              hipStream_t stream) {
    const float* x     = (const float*)d_in[0];
    const float* rw    = (const float*)d_in[1];
    const float* rb    = (const float*)d_in[2];
    const float* gup   = (const float*)d_in[3];
    const float* gup_b = (const float*)d_in[4];
    const float* dw    = (const float*)d_in[5];
    const float* db    = (const float*)d_in[6];
    float* out    = (float*)d_out;
    float* scores = out + (size_t)T_TOK * H_DIM;

    char* ws = (char*)d_ws;
    int*   counts   = (int*)(ws + WS_COUNTS);
    int*   offsets  = (int*)(ws + WS_OFFSETS);
    int*   tok_e    = (int*)(ws + WS_TOKE);
    int*   tok_p    = (int*)(ws + WS_TOKP);
    float* tok_w    = (float*)(ws + WS_TOKW);
    int*   tok_g    = (int*)(ws + WS_TOKG);
    int*   slot_tok = (int*)(ws + WS_SLOTTOK);
    u16*   xg       = (u16*)(ws + WS_XG);
    u16*   gated    = (u16*)(ws + WS_GATED);
    float* outws    = (float*)(ws + WS_OUT);

    k_zero<<<1, 64, 0, stream>>>(counts);
    k_router<<<T_TOK, 64, 0, stream>>>(x, rw, rb, scores, counts, tok_e, tok_p, tok_w);
    k_offsets<<<1, 64, 0, stream>>>(counts, offsets);
    k_build<<<(2*T_TOK + 255)/256, 256, 0, stream>>>(tok_e, tok_p, offsets, tok_g, slot_tok);
    k_gather<<<2*T_TOK, 256, 0, stream>>>(x, slot_tok, xg);
    dim3 g2(M_DIM/64, 16, E_NUM);
    k_gateup<<<g2, 256, 0, stream>>>(xg, gup, gup_b, counts, offsets, gated);
    dim3 g3(H_DIM/64, 16, E_NUM);
    k_down<<<g3, 256, 0, stream>>>(gated, dw, counts, offsets, outws);
    k_final<<<T_TOK, 256, 0, stream>>>(outws, db, tok_e, tok_g, tok_w, out);
}

// Round 3
// 368.937 us; speedup vs baseline: 3.2571x; 1.0583x over previous
//
#include <hip/hip_runtime.h>
#include <hip/hip_bf16.h>
#include <cstdint>
#include <cstddef>

typedef unsigned short u16;
typedef __bf16 v8bf __attribute__((ext_vector_type(8)));
typedef float v4f __attribute__((ext_vector_type(4)));

#define T_TOK 1024
#define H_DIM 1024
#define E_NUM 16
#define M_DIM 4096
#define GU_DIM 8192
#define ALPHA 1.702f
#define LIMIT 7.0f
#define LDSTR 40   // ushorts per LDS row: 32 data + 8 pad = 80 B (5x16B slots -> 2-way max on b128)

// workspace layout (byte offsets)
#define WS_COUNTS   0
#define WS_OFFSETS  256
#define WS_TOKE     512
#define WS_TOKP     (WS_TOKE + 8192)
#define WS_TOKW     (WS_TOKP + 8192)
#define WS_TOKG     (WS_TOKW + 8192)
#define WS_SLOTTOK  (WS_TOKG + 8192)
#define WS_XG       65536                                  // 2048*1024 bf16 = 4 MB
#define WS_GATED    (WS_XG + 2048*1024*2)                  // 2048*4096 bf16 = 16 MB
#define WS_OUT      (WS_GATED + (size_t)2048*4096*2)       // 2048*1024 f32 = 8 MB

static __device__ __forceinline__ u16 f2bf(float f) {
    union { __hip_bfloat16 b; u16 u; } cv;
    cv.b = __float2bfloat16(f);
    return cv.u;
}

__global__ __launch_bounds__(64) void k_zero(int* counts) {
    if (threadIdx.x < E_NUM) counts[threadIdx.x] = 0;
}

__global__ __launch_bounds__(64) void k_router(
    const float* __restrict__ x, const float* __restrict__ rw, const float* __restrict__ rb,
    float* __restrict__ scores, int* __restrict__ counts,
    int* __restrict__ tok_e, int* __restrict__ tok_p, float* __restrict__ tok_w)
{
    const int t = blockIdx.x;
    const int lane = threadIdx.x;
    float part[E_NUM];
#pragma unroll
    for (int e = 0; e < E_NUM; ++e) part[e] = 0.f;
    const float* xrow = x + (size_t)t * H_DIM;
    for (int h = lane; h < H_DIM; h += 64) {
        float xv = xrow[h];
        const float* wrow = rw + (size_t)h * E_NUM;
#pragma unroll
        for (int e = 0; e < E_NUM; ++e) part[e] = fmaf(xv, wrow[e], part[e]);
    }
    __shared__ float red[64][E_NUM];
    __shared__ float logits[E_NUM];
    __shared__ int se[2];
    __shared__ float sw[2];
#pragma unroll
    for (int e = 0; e < E_NUM; ++e) red[lane][e] = part[e];
    __syncthreads();
    if (lane < E_NUM) {
        float s = rb[lane];
        for (int l = 0; l < 64; ++l) s += red[l][lane];
        logits[lane] = s;
    }
    __syncthreads();
    if (lane == 0) {
        int i0 = 0; float v0 = logits[0];
        for (int e = 1; e < E_NUM; ++e) { float v = logits[e]; if (v > v0) { v0 = v; i0 = e; } }
        int i1 = -1; float v1 = -3.4e38f;
        for (int e = 0; e < E_NUM; ++e) {
            if (e == i0) continue;
            float v = logits[e];
            if (v > v1) { v1 = v; i1 = e; }
        }
        float ex = expf(v1 - v0);
        float w0 = 1.f / (1.f + ex);
        float w1 = ex / (1.f + ex);
        int p0 = atomicAdd(&counts[i0], 1);
        int p1 = atomicAdd(&counts[i1], 1);
        tok_e[2*t]   = i0; tok_p[2*t]   = p0; tok_w[2*t]   = w0;
        tok_e[2*t+1] = i1; tok_p[2*t+1] = p1; tok_w[2*t+1] = w1;
        se[0] = i0; se[1] = i1; sw[0] = w0; sw[1] = w1;
    }
    __syncthreads();
    if (lane < E_NUM) {
        float v = 0.f;
        if (lane == se[0]) v = sw[0];
        else if (lane == se[1]) v = sw[1];
        scores[(size_t)t * E_NUM + lane] = v;
    }
}

__global__ __launch_bounds__(64) void k_offsets(const int* __restrict__ counts, int* __restrict__ offsets) {
    if (threadIdx.x == 0) {
        int acc = 0;
        for (int e = 0; e < E_NUM; ++e) { offsets[e] = acc; acc += counts[e]; }
        offsets[E_NUM] = acc;
    }
}

__global__ __launch_bounds__(256) void k_build(
    const int* __restrict__ tok_e, const int* __restrict__ tok_p, const int* __restrict__ offsets,
    int* __restrict__ tok_g, int* __restrict__ slot_tok)
{
    int i = blockIdx.x * blockDim.x + threadIdx.x;
    if (i >= 2 * T_TOK) return;
    int e = tok_e[i], p = tok_p[i];
    int g = offsets[e] + p;
    tok_g[i] = g;
    slot_tok[g] = i >> 1;
}

__global__ __launch_bounds__(256) void k_gather(
    const float* __restrict__ x, const int* __restrict__ slot_tok, u16* __restrict__ xg)
{
    const int g = blockIdx.x;
    const int t = slot_tok[g];
    const float4* src = (const float4*)(x + (size_t)t * H_DIM);
    float4 v = src[threadIdx.x];
    ushort4 o;
    o.x = f2bf(v.x); o.y = f2bf(v.y); o.z = f2bf(v.z); o.w = f2bf(v.w);
    *(ushort4*)&xg[(size_t)g * H_DIM + threadIdx.x * 4] = o;
}

// ---------------- gate_up MFMA GEMM ----------------
// BM=256 rows (slots) so weights stream exactly once; 64 m per block
// (=128 interleaved W cols), BK=32, 512 threads = 8 waves x 32 rows.
// LDS cols 0..63 = gate(m), 64..127 = up(m).
__global__ __launch_bounds__(512) void k_gateup(
    const u16* __restrict__ xg, const float* __restrict__ W, const float* __restrict__ bias,
    const int* __restrict__ counts, const int* __restrict__ offsets,
    u16* __restrict__ gated)
{
    const int e = blockIdx.z;
    const int cnt = counts[e];
    const int row0 = blockIdx.y * 256;
    if (row0 >= cnt) return;
    const int m0 = blockIdx.x * 64;
    const int off = offsets[e];
    __shared__ u16 As[256 * LDSTR];
    __shared__ u16 Bs[128 * LDSTR];
    const int tid = threadIdx.x;
    const int lane = tid & 63;
    const int w = tid >> 6;
    const bool active = (row0 + w * 32) < cnt;

    // A staging: 1024 16B-chunks (256 rows x 4 segs), 2 per thread
    const int ar0 = tid >> 2, aseg = tid & 3;
    const int ar1 = ar0 + 128;
    int gr0 = row0 + ar0; if (gr0 >= cnt) gr0 = cnt - 1;
    int gr1 = row0 + ar1; if (gr1 >= cnt) gr1 = cnt - 1;
    const u16* aP0 = xg + (size_t)(off + gr0) * H_DIM + aseg * 8;
    const u16* aP1 = xg + (size_t)(off + gr1) * H_DIM + aseg * 8;

    // B staging: 512 strips (128 cols x 4 k-strips of 8), 1 per thread
    const int bn   = tid & 127;
    const int bk0  = (tid >> 7) * 8;                 // 0,8,16,24
    const int bcol = (bn >> 1) + (bn & 1) * 64;      // de-interleave: even->gate, odd->up
    const float* bP = W + (size_t)e * H_DIM * GU_DIM + (size_t)bk0 * GU_DIM + 2 * m0 + bn;

    uint4 ra0, ra1;
    float rb[8];
    v4f acc0[8], acc1[8];
    v4f zz = {0.f, 0.f, 0.f, 0.f};
#pragma unroll
    for (int f = 0; f < 8; ++f) { acc0[f] = zz; acc1[f] = zz; }

    const u16* aF = &As[(w * 32 + (lane & 15)) * LDSTR + (lane >> 4) * 8];
    const u16* bF = &Bs[(lane & 15) * LDSTR + (lane >> 4) * 8];

#define GU_LOAD(K0)                                                       \
    ra0 = *(const uint4*)(aP0 + (K0));                                    \
    ra1 = *(const uint4*)(aP1 + (K0));                                    \
    _Pragma("unroll")                                                     \
    for (int i = 0; i < 8; ++i) rb[i] = bP[(size_t)((K0) + i) * GU_DIM];

    GU_LOAD(0)
    for (int kt = 0; kt < H_DIM / 32; ++kt) {
        *(uint4*)&As[ar0 * LDSTR + aseg * 8] = ra0;
        *(uint4*)&As[ar1 * LDSTR + aseg * 8] = ra1;
        uint4 p0;
        p0.x = f2bf(rb[0]) | ((unsigned)f2bf(rb[1]) << 16);
        p0.y = f2bf(rb[2]) | ((unsigned)f2bf(rb[3]) << 16);
        p0.z = f2bf(rb[4]) | ((unsigned)f2bf(rb[5]) << 16);
        p0.w = f2bf(rb[6]) | ((unsigned)f2bf(rb[7]) << 16);
        *(uint4*)&Bs[bcol * LDSTR + bk0] = p0;
        __syncthreads();
        if (kt + 1 < H_DIM / 32) { GU_LOAD((kt + 1) * 32) }
        if (active) {
            v8bf a0 = *(const v8bf*)aF;
            v8bf a1 = *(const v8bf*)(aF + 16 * LDSTR);
#pragma unroll
            for (int f = 0; f < 8; ++f) {
                v8bf b = *(const v8bf*)(bF + f * 16 * LDSTR);
                acc0[f] = __builtin_amdgcn_mfma_f32_16x16x32_bf16(a0, b, acc0[f], 0, 0, 0);
                acc1[f] = __builtin_amdgcn_mfma_f32_16x16x32_bf16(a1, b, acc1[f], 0, 0, 0);
            }
        }
        __syncthreads();
    }
#undef GU_LOAD

    if (!active) return;
    const float* bg = bias + (size_t)e * GU_DIM + 2 * m0;
#pragma unroll
    for (int i = 0; i < 2; ++i) {
#pragma unroll
        for (int r = 0; r < 4; ++r) {
            int rr = row0 + w * 32 + i * 16 + (lane >> 4) * 4 + r;
            if (rr >= cnt) continue;
            u16* orow = gated + (size_t)(off + rr) * M_DIM + m0;
#pragma unroll
            for (int f = 0; f < 4; ++f) {
                int ml = f * 16 + (lane & 15);
                float g = (i ? acc1[f][r]     : acc0[f][r])     + bg[2 * ml];
                float u = (i ? acc1[f + 4][r] : acc0[f + 4][r]) + bg[2 * ml + 1];
                g = fminf(g, LIMIT); g = fmaxf(g, -1e9f);
                u = fminf(fmaxf(u, -LIMIT), LIMIT);
                float glu = g / (1.f + expf(-ALPHA * g));
                orow[ml] = f2bf((u + 1.f) * glu);
            }
        }
    }
}

// ---------------- down MFMA GEMM ----------------
// BM=256, BN=64, BK=32, 512 threads = 8 waves x 32 rows
__global__ __launch_bounds__(512) void k_down(
    const u16* __restrict__ gated, const float* __restrict__ W,
    const int* __restrict__ counts, const int* __restrict__ offsets,
    float* __restrict__ outws)
{
    const int e = blockIdx.z;
    const int cnt = counts[e];
    const int row0 = blockIdx.y * 256;
    if (row0 >= cnt) return;
    const int c0 = blockIdx.x * 64;
    const int off = offsets[e];
    __shared__ u16 As[256 * LDSTR];
    __shared__ u16 Bs[64 * LDSTR];
    const int tid = threadIdx.x;
    const int lane = tid & 63;
    const int w = tid >> 6;
    const bool active = (row0 + w * 32) < cnt;

    const int ar0 = tid >> 2, aseg = tid & 3;
    const int ar1 = ar0 + 128;
    int gr0 = row0 + ar0; if (gr0 >= cnt) gr0 = cnt - 1;
    int gr1 = row0 + ar1; if (gr1 >= cnt) gr1 = cnt - 1;
    const u16* aP0 = gated + (size_t)(off + gr0) * M_DIM + aseg * 8;
    const u16* aP1 = gated + (size_t)(off + gr1) * M_DIM + aseg * 8;

    // B staging: 64 cols x 8 k-strips of 4, 1 strip per thread
    const int bn  = tid & 63;
    const int bk0 = (tid >> 6) * 4;          // 0,4,...,28
    const float* bP = W + (size_t)e * M_DIM * H_DIM + (size_t)bk0 * H_DIM + c0 + bn;

    uint4 ra0, ra1;
    float rb[4];
    v4f acc0[4], acc1[4];
    v4f zz = {0.f, 0.f, 0.f, 0.f};
#pragma unroll
    for (int f = 0; f < 4; ++f) { acc0[f] = zz; acc1[f] = zz; }

    const u16* aF = &As[(w * 32 + (lane & 15)) * LDSTR + (lane >> 4) * 8];
    const u16* bF = &Bs[(lane & 15) * LDSTR + (lane >> 4) * 8];

#define DN_LOAD(K0)                                                       \
    ra0 = *(const uint4*)(aP0 + (K0));                                    \
    ra1 = *(const uint4*)(aP1 + (K0));                                    \
    _Pragma("unroll")                                                     \
    for (int i = 0; i < 4; ++i) rb[i] = bP[(size_t)((K0) + i) * H_DIM];

    DN_LOAD(0)
    for (int kt = 0; kt < M_DIM / 32; ++kt) {
        *(uint4*)&As[ar0 * LDSTR + aseg * 8] = ra0;
        *(uint4*)&As[ar1 * LDSTR + aseg * 8] = ra1;
        uint2 p0;
        p0.x = f2bf(rb[0]) | ((unsigned)f2bf(rb[1]) << 16);
        p0.y = f2bf(rb[2]) | ((unsigned)f2bf(rb[3]) << 16);
        *(uint2*)&Bs[bn * LDSTR + bk0] = p0;
        __syncthreads();
        if (kt + 1 < M_DIM / 32) { DN_LOAD((kt + 1) * 32) }
        if (active) {
            v8bf a0 = *(const v8bf*)aF;
            v8bf a1 = *(const v8bf*)(aF + 16 * LDSTR);
#pragma unroll
            for (int f = 0; f < 4; ++f) {
                v8bf b = *(const v8bf*)(bF + f * 16 * LDSTR);
                acc0[f] = __builtin_amdgcn_mfma_f32_16x16x32_bf16(a0, b, acc0[f], 0, 0, 0);
                acc1[f] = __builtin_amdgcn_mfma_f32_16x16x32_bf16(a1, b, acc1[f], 0, 0, 0);
            }
        }
        __syncthreads();
    }
#undef DN_LOAD

    if (!active) return;
#pragma unroll
    for (int i = 0; i < 2; ++i) {
#pragma unroll
        for (int r = 0; r < 4; ++r) {
            int rr = row0 + w * 32 + i * 16 + (lane >> 4) * 4 + r;
            if (rr >= cnt) continue;
            float* orow = outws + (size_t)(off + rr) * H_DIM + c0;
#pragma unroll
            for (int f = 0; f < 4; ++f) {
                orow[f * 16 + (lane & 15)] = (i ? acc1[f][r] : acc0[f][r]);
            }
        }
    }
}

__global__ __launch_bounds__(256) void k_final(
    const float* __restrict__ outws, const float* __restrict__ db,
    const int* __restrict__ tok_e, const int* __restrict__ tok_g, const float* __restrict__ tok_w,
    float* __restrict__ out)
{
    const int t = blockIdx.x;
    const int tid = threadIdx.x;
    const int h = tid << 2;
    const int e0 = tok_e[2*t], e1 = tok_e[2*t+1];
    const int g0 = tok_g[2*t], g1 = tok_g[2*t+1];
    const float w0 = tok_w[2*t], w1 = tok_w[2*t+1];
    float4 o0 = *(const float4*)(outws + (size_t)g0 * H_DIM + h);
    float4 o1 = *(const float4*)(outws + (size_t)g1 * H_DIM + h);
    float4 b0 = *(const float4*)(db + (size_t)e0 * H_DIM + h);
    float4 b1 = *(const float4*)(db + (size_t)e1 * H_DIM + h);
    float4 r;
    r.x = w0 * (o0.x + b0.x) + w1 * (o1.x + b1.x);
    r.y = w0 * (o0.y + b0.y) + w1 * (o1.y + b1.y);
    r.z = w0 * (o0.z + b0.z) + w1 * (o1.z + b1.z);
    r.w = w0 * (o0.w + b0.w) + w1 * (o1.w + b1.w);
    *(float4*)(out + (size_t)t * H_DIM + h) = r;
}

extern "C" void kernel_launch(void* const* d_in, const int* in_sizes, int n_in,
                              void* d_out, int out_size, void* d_ws, size_t ws_size,
                              hipStream_t stream) {
    const float* x     = (const float*)d_in[0];
    const float* rw    = (const float*)d_in[1];
    const float* rb    = (const float*)d_in[2];
    const float* gup   = (const float*)d_in[3];
    const float* gup_b = (const float*)d_in[4];
    const float* dw    = (const float*)d_in[5];
    const float* db    = (const float*)d_in[6];
    float* out    = (float*)d_out;
    float* scores = out + (size_t)T_TOK * H_DIM;

    char* ws = (char*)d_ws;
    int*   counts   = (int*)(ws + WS_COUNTS);
    int*   offsets  = (int*)(ws + WS_OFFSETS);
    int*   tok_e    = (int*)(ws + WS_TOKE);
    int*   tok_p    = (int*)(ws + WS_TOKP);
    float* tok_w    = (float*)(ws + WS_TOKW);
    int*   tok_g    = (int*)(ws + WS_TOKG);
    int*   slot_tok = (int*)(ws + WS_SLOTTOK);
    u16*   xg       = (u16*)(ws + WS_XG);
    u16*   gated    = (u16*)(ws + WS_GATED);
    float* outws    = (float*)(ws + WS_OUT);

    k_zero<<<1, 64, 0, stream>>>(counts);
    k_router<<<T_TOK, 64, 0, stream>>>(x, rw, rb, scores, counts, tok_e, tok_p, tok_w);
    k_offsets<<<1, 64, 0, stream>>>(counts, offsets);
    k_build<<<(2*T_TOK + 255)/256, 256, 0, stream>>>(tok_e, tok_p, offsets, tok_g, slot_tok);
    k_gather<<<2*T_TOK, 256, 0, stream>>>(x, slot_tok, xg);
    dim3 g2(M_DIM/64, 8, E_NUM);
    k_gateup<<<g2, 512, 0, stream>>>(xg, gup, gup_b, counts, offsets, gated);
    dim3 g3(H_DIM/64, 8, E_NUM);
    k_down<<<g3, 512, 0, stream>>>(gated, dw, counts, offsets, outws);
    k_final<<<T_TOK, 256, 0, stream>>>(outws, db, tok_e, tok_g, tok_w, out);
}

// Round 4
// 270.075 us; speedup vs baseline: 4.4493x; 1.3661x over previous
//
#include <hip/hip_runtime.h>
#include <hip/hip_bf16.h>
#include <cstdint>
#include <cstddef>

typedef unsigned short u16;
typedef __bf16 v8bf __attribute__((ext_vector_type(8)));
typedef float v4f __attribute__((ext_vector_type(4)));

#define T_TOK 1024
#define H_DIM 1024
#define E_NUM 16
#define M_DIM 4096
#define GU_DIM 8192
#define ALPHA 1.702f
#define LIMIT 7.0f
#define LDSTR 40   // ushorts per LDS row: 32 data + 8 pad = 80 B
#define KSPL 4     // split-K factor for k_down

// workspace layout (byte offsets)
#define WS_COUNTS   0
#define WS_OFFSETS  256
#define WS_TOKE     512
#define WS_TOKP     (WS_TOKE + 8192)
#define WS_TOKW     (WS_TOKP + 8192)
#define WS_TOKG     (WS_TOKW + 8192)
#define WS_SLOTTOK  (WS_TOKG + 8192)
#define WS_XG       65536                                  // 2048*1024 bf16 = 4 MB
#define WS_GATED    (WS_XG + 2048*1024*2)                  // 2048*4096 bf16 = 16 MB
#define WS_OUT      (WS_GATED + (size_t)2048*4096*2)       // KSPL*2048*1024 f32 = 32 MB

static __device__ __forceinline__ u16 f2bf(float f) {
    union { __hip_bfloat16 b; u16 u; } cv;
    cv.b = __float2bfloat16(f);
    return cv.u;
}

__global__ __launch_bounds__(64) void k_zero(int* counts) {
    if (threadIdx.x < E_NUM) counts[threadIdx.x] = 0;
}

__global__ __launch_bounds__(64) void k_router(
    const float* __restrict__ x, const float* __restrict__ rw, const float* __restrict__ rb,
    float* __restrict__ scores, int* __restrict__ counts,
    int* __restrict__ tok_e, int* __restrict__ tok_p, float* __restrict__ tok_w)
{
    const int t = blockIdx.x;
    const int lane = threadIdx.x;
    float part[E_NUM];
#pragma unroll
    for (int e = 0; e < E_NUM; ++e) part[e] = 0.f;
    const float* xrow = x + (size_t)t * H_DIM;
    for (int h = lane; h < H_DIM; h += 64) {
        float xv = xrow[h];
        const float* wrow = rw + (size_t)h * E_NUM;
#pragma unroll
        for (int e = 0; e < E_NUM; ++e) part[e] = fmaf(xv, wrow[e], part[e]);
    }
    __shared__ float red[64][E_NUM];
    __shared__ float logits[E_NUM];
    __shared__ int se[2];
    __shared__ float sw[2];
#pragma unroll
    for (int e = 0; e < E_NUM; ++e) red[lane][e] = part[e];
    __syncthreads();
    if (lane < E_NUM) {
        float s = rb[lane];
        for (int l = 0; l < 64; ++l) s += red[l][lane];
        logits[lane] = s;
    }
    __syncthreads();
    if (lane == 0) {
        int i0 = 0; float v0 = logits[0];
        for (int e = 1; e < E_NUM; ++e) { float v = logits[e]; if (v > v0) { v0 = v; i0 = e; } }
        int i1 = -1; float v1 = -3.4e38f;
        for (int e = 0; e < E_NUM; ++e) {
            if (e == i0) continue;
            float v = logits[e];
            if (v > v1) { v1 = v; i1 = e; }
        }
        float ex = expf(v1 - v0);
        float w0 = 1.f / (1.f + ex);
        float w1 = ex / (1.f + ex);
        int p0 = atomicAdd(&counts[i0], 1);
        int p1 = atomicAdd(&counts[i1], 1);
        tok_e[2*t]   = i0; tok_p[2*t]   = p0; tok_w[2*t]   = w0;
        tok_e[2*t+1] = i1; tok_p[2*t+1] = p1; tok_w[2*t+1] = w1;
        se[0] = i0; se[1] = i1; sw[0] = w0; sw[1] = w1;
    }
    __syncthreads();
    if (lane < E_NUM) {
        float v = 0.f;
        if (lane == se[0]) v = sw[0];
        else if (lane == se[1]) v = sw[1];
        scores[(size_t)t * E_NUM + lane] = v;
    }
}

__global__ __launch_bounds__(64) void k_offsets(const int* __restrict__ counts, int* __restrict__ offsets) {
    if (threadIdx.x == 0) {
        int acc = 0;
        for (int e = 0; e < E_NUM; ++e) { offsets[e] = acc; acc += counts[e]; }
        offsets[E_NUM] = acc;
    }
}

__global__ __launch_bounds__(256) void k_build(
    const int* __restrict__ tok_e, const int* __restrict__ tok_p, const int* __restrict__ offsets,
    int* __restrict__ tok_g, int* __restrict__ slot_tok)
{
    int i = blockIdx.x * blockDim.x + threadIdx.x;
    if (i >= 2 * T_TOK) return;
    int e = tok_e[i], p = tok_p[i];
    int g = offsets[e] + p;
    tok_g[i] = g;
    slot_tok[g] = i >> 1;
}

__global__ __launch_bounds__(256) void k_gather(
    const float* __restrict__ x, const int* __restrict__ slot_tok, u16* __restrict__ xg)
{
    const int g = blockIdx.x;
    const int t = slot_tok[g];
    const float4* src = (const float4*)(x + (size_t)t * H_DIM);
    float4 v = src[threadIdx.x];
    ushort4 o;
    o.x = f2bf(v.x); o.y = f2bf(v.y); o.z = f2bf(v.z); o.w = f2bf(v.w);
    *(ushort4*)&xg[(size_t)g * H_DIM + threadIdx.x * 4] = o;
}

// ---------------- gate_up MFMA GEMM ----------------
// BM=256 rows, 64 m per block (=128 interleaved W cols), BK=32, 512 thr = 8 waves.
// B (HBM weight stream) register-prefetched 2 tiles deep; A 1 tile deep.
__global__ __launch_bounds__(512) void k_gateup(
    const u16* __restrict__ xg, const float* __restrict__ W, const float* __restrict__ bias,
    const int* __restrict__ counts, const int* __restrict__ offsets,
    u16* __restrict__ gated)
{
    const int e = blockIdx.z;
    const int cnt = counts[e];
    const int row0 = blockIdx.y * 256;
    if (row0 >= cnt) return;
    const int m0 = blockIdx.x * 64;
    const int off = offsets[e];
    __shared__ u16 As[256 * LDSTR];
    __shared__ u16 Bs[128 * LDSTR];
    const int tid = threadIdx.x;
    const int lane = tid & 63;
    const int w = tid >> 6;
    const bool active = (row0 + w * 32) < cnt;

    const int ar0 = tid >> 2, aseg = tid & 3;
    const int ar1 = ar0 + 128;
    int gr0 = row0 + ar0; if (gr0 >= cnt) gr0 = cnt - 1;
    int gr1 = row0 + ar1; if (gr1 >= cnt) gr1 = cnt - 1;
    const u16* aP0 = xg + (size_t)(off + gr0) * H_DIM + aseg * 8;
    const u16* aP1 = xg + (size_t)(off + gr1) * H_DIM + aseg * 8;

    const int bn   = tid & 127;
    const int bk0  = (tid >> 7) * 8;                 // 0,8,16,24
    const int bcol = (bn >> 1) + (bn & 1) * 64;      // de-interleave even->gate, odd->up
    const float* bP = W + (size_t)e * H_DIM * GU_DIM + (size_t)bk0 * GU_DIM + 2 * m0 + bn;

    uint4 ra0, ra1;
    float rbA[8], rbB[8];
    v4f acc0[8], acc1[8];
    v4f zz = {0.f, 0.f, 0.f, 0.f};
#pragma unroll
    for (int f = 0; f < 8; ++f) { acc0[f] = zz; acc1[f] = zz; }

    const u16* aF = &As[(w * 32 + (lane & 15)) * LDSTR + (lane >> 4) * 8];
    const u16* bF = &Bs[(lane & 15) * LDSTR + (lane >> 4) * 8];

#define GU_LOADA(K0)                                                      \
    ra0 = *(const uint4*)(aP0 + (K0));                                    \
    ra1 = *(const uint4*)(aP1 + (K0));

#define GU_LOADB(K0, dst)                                                 \
    _Pragma("unroll")                                                     \
    for (int i = 0; i < 8; ++i) dst[i] = bP[(size_t)((K0) + i) * GU_DIM];

#define GU_STORE(rbX)                                                     \
    *(uint4*)&As[ar0 * LDSTR + aseg * 8] = ra0;                           \
    *(uint4*)&As[ar1 * LDSTR + aseg * 8] = ra1;                           \
    {                                                                     \
        uint4 p0;                                                         \
        p0.x = f2bf(rbX[0]) | ((unsigned)f2bf(rbX[1]) << 16);             \
        p0.y = f2bf(rbX[2]) | ((unsigned)f2bf(rbX[3]) << 16);             \
        p0.z = f2bf(rbX[4]) | ((unsigned)f2bf(rbX[5]) << 16);             \
        p0.w = f2bf(rbX[6]) | ((unsigned)f2bf(rbX[7]) << 16);             \
        *(uint4*)&Bs[bcol * LDSTR + bk0] = p0;                            \
    }

#define GU_MFMA                                                           \
    if (active) {                                                         \
        v8bf a0 = *(const v8bf*)aF;                                       \
        v8bf a1 = *(const v8bf*)(aF + 16 * LDSTR);                        \
        _Pragma("unroll")                                                 \
        for (int f = 0; f < 8; ++f) {                                     \
            v8bf b = *(const v8bf*)(bF + f * 16 * LDSTR);                 \
            acc0[f] = __builtin_amdgcn_mfma_f32_16x16x32_bf16(a0, b, acc0[f], 0, 0, 0); \
            acc1[f] = __builtin_amdgcn_mfma_f32_16x16x32_bf16(a1, b, acc1[f], 0, 0, 0); \
        }                                                                 \
    }

    GU_LOADA(0)
    GU_LOADB(0, rbA)
    GU_LOADB(32, rbB)
    for (int k0 = 0; k0 < H_DIM; k0 += 64) {
        // tile at k0 (ra holds k0, rbA holds k0)
        GU_STORE(rbA)
        __syncthreads();
        GU_LOADA(k0 + 32)
        if (k0 + 64 < H_DIM) { GU_LOADB(k0 + 64, rbA) }
        GU_MFMA
        __syncthreads();
        // tile at k0+32 (ra holds k0+32, rbB holds k0+32)
        GU_STORE(rbB)
        __syncthreads();
        if (k0 + 64 < H_DIM) { GU_LOADA(k0 + 64) }
        if (k0 + 96 < H_DIM) { GU_LOADB(k0 + 96, rbB) }
        GU_MFMA
        __syncthreads();
    }
#undef GU_LOADA
#undef GU_LOADB
#undef GU_STORE
#undef GU_MFMA

    if (!active) return;
    const float* bg = bias + (size_t)e * GU_DIM + 2 * m0;
#pragma unroll
    for (int i = 0; i < 2; ++i) {
#pragma unroll
        for (int r = 0; r < 4; ++r) {
            int rr = row0 + w * 32 + i * 16 + (lane >> 4) * 4 + r;
            if (rr >= cnt) continue;
            u16* orow = gated + (size_t)(off + rr) * M_DIM + m0;
#pragma unroll
            for (int f = 0; f < 4; ++f) {
                int ml = f * 16 + (lane & 15);
                float g = (i ? acc1[f][r]     : acc0[f][r])     + bg[2 * ml];
                float u = (i ? acc1[f + 4][r] : acc0[f + 4][r]) + bg[2 * ml + 1];
                g = fminf(g, LIMIT); g = fmaxf(g, -1e9f);
                u = fminf(fmaxf(u, -LIMIT), LIMIT);
                float glu = g / (1.f + expf(-ALPHA * g));
                orow[ml] = f2bf((u + 1.f) * glu);
            }
        }
    }
}

// ---------------- down MFMA GEMM (split-K) ----------------
// BM=256, BN=64, BK=32, 512 thr = 8 waves; K split into KSPL chunks of 1024.
// blockIdx.x = ntile (0..15) | kc<<4
__global__ __launch_bounds__(512) void k_down(
    const u16* __restrict__ gated, const float* __restrict__ W,
    const int* __restrict__ counts, const int* __restrict__ offsets,
    float* __restrict__ outws)
{
    const int e = blockIdx.z;
    const int cnt = counts[e];
    const int row0 = blockIdx.y * 256;
    if (row0 >= cnt) return;
    const int ntile = blockIdx.x & 15;
    const int kc = blockIdx.x >> 4;
    const int c0 = ntile * 64;
    const int kbase = kc * (M_DIM / KSPL);          // 1024 k per chunk
    const int off = offsets[e];
    __shared__ u16 As[256 * LDSTR];
    __shared__ u16 Bs[64 * LDSTR];
    const int tid = threadIdx.x;
    const int lane = tid & 63;
    const int w = tid >> 6;
    const bool active = (row0 + w * 32) < cnt;

    const int ar0 = tid >> 2, aseg = tid & 3;
    const int ar1 = ar0 + 128;
    int gr0 = row0 + ar0; if (gr0 >= cnt) gr0 = cnt - 1;
    int gr1 = row0 + ar1; if (gr1 >= cnt) gr1 = cnt - 1;
    const u16* aP0 = gated + (size_t)(off + gr0) * M_DIM + kbase + aseg * 8;
    const u16* aP1 = gated + (size_t)(off + gr1) * M_DIM + kbase + aseg * 8;

    const int bn  = tid & 63;
    const int bk0 = (tid >> 6) * 4;          // 0,4,...,28
    const float* bP = W + (size_t)e * M_DIM * H_DIM + (size_t)(kbase + bk0) * H_DIM + c0 + bn;

    uint4 ra0, ra1;
    float rbA[4], rbB[4];
    v4f acc0[4], acc1[4];
    v4f zz = {0.f, 0.f, 0.f, 0.f};
#pragma unroll
    for (int f = 0; f < 4; ++f) { acc0[f] = zz; acc1[f] = zz; }

    const u16* aF = &As[(w * 32 + (lane & 15)) * LDSTR + (lane >> 4) * 8];
    const u16* bF = &Bs[(lane & 15) * LDSTR + (lane >> 4) * 8];

#define DN_LOADA(K0)                                                      \
    ra0 = *(const uint4*)(aP0 + (K0));                                    \
    ra1 = *(const uint4*)(aP1 + (K0));

#define DN_LOADB(K0, dst)                                                 \
    _Pragma("unroll")                                                     \
    for (int i = 0; i < 4; ++i) dst[i] = bP[(size_t)((K0) + i) * H_DIM];

#define DN_STORE(rbX)                                                     \
    *(uint4*)&As[ar0 * LDSTR + aseg * 8] = ra0;                           \
    *(uint4*)&As[ar1 * LDSTR + aseg * 8] = ra1;                           \
    {                                                                     \
        uint2 p0;                                                         \
        p0.x = f2bf(rbX[0]) | ((unsigned)f2bf(rbX[1]) << 16);             \
        p0.y = f2bf(rbX[2]) | ((unsigned)f2bf(rbX[3]) << 16);             \
        *(uint2*)&Bs[bn * LDSTR + bk0] = p0;                              \
    }

#define DN_MFMA                                                           \
    if (active) {                                                         \
        v8bf a0 = *(const v8bf*)aF;                                       \
        v8bf a1 = *(const v8bf*)(aF + 16 * LDSTR);                        \
        _Pragma("unroll")                                                 \
        for (int f = 0; f < 4; ++f) {                                     \
            v8bf b = *(const v8bf*)(bF + f * 16 * LDSTR);                 \
            acc0[f] = __builtin_amdgcn_mfma_f32_16x16x32_bf16(a0, b, acc0[f], 0, 0, 0); \
            acc1[f] = __builtin_amdgcn_mfma_f32_16x16x32_bf16(a1, b, acc1[f], 0, 0, 0); \
        }                                                                 \
    }

    const int KC = M_DIM / KSPL;
    DN_LOADA(0)
    DN_LOADB(0, rbA)
    DN_LOADB(32, rbB)
    for (int k0 = 0; k0 < KC; k0 += 64) {
        DN_STORE(rbA)
        __syncthreads();
        DN_LOADA(k0 + 32)
        if (k0 + 64 < KC) { DN_LOADB(k0 + 64, rbA) }
        DN_MFMA
        __syncthreads();
        DN_STORE(rbB)
        __syncthreads();
        if (k0 + 64 < KC) { DN_LOADA(k0 + 64) }
        if (k0 + 96 < KC) { DN_LOADB(k0 + 96, rbB) }
        DN_MFMA
        __syncthreads();
    }
#undef DN_LOADA
#undef DN_LOADB
#undef DN_STORE
#undef DN_MFMA

    if (!active) return;
    float* outp = outws + (size_t)kc * 2048 * H_DIM;
#pragma unroll
    for (int i = 0; i < 2; ++i) {
#pragma unroll
        for (int r = 0; r < 4; ++r) {
            int rr = row0 + w * 32 + i * 16 + (lane >> 4) * 4 + r;
            if (rr >= cnt) continue;
            float* orow = outp + (size_t)(off + rr) * H_DIM + c0;
#pragma unroll
            for (int f = 0; f < 4; ++f) {
                orow[f * 16 + (lane & 15)] = (i ? acc1[f][r] : acc0[f][r]);
            }
        }
    }
}

__global__ __launch_bounds__(256) void k_final(
    const float* __restrict__ outws, const float* __restrict__ db,
    const int* __restrict__ tok_e, const int* __restrict__ tok_g, const float* __restrict__ tok_w,
    float* __restrict__ out)
{
    const int t = blockIdx.x;
    const int tid = threadIdx.x;
    const int h = tid << 2;
    const int e0 = tok_e[2*t], e1 = tok_e[2*t+1];
    const int g0 = tok_g[2*t], g1 = tok_g[2*t+1];
    const float w0 = tok_w[2*t], w1 = tok_w[2*t+1];
    float4 o0 = {0,0,0,0}, o1 = {0,0,0,0};
#pragma unroll
    for (int p = 0; p < KSPL; ++p) {
        const float* base = outws + (size_t)p * 2048 * H_DIM;
        float4 a = *(const float4*)(base + (size_t)g0 * H_DIM + h);
        float4 b = *(const float4*)(base + (size_t)g1 * H_DIM + h);
        o0.x += a.x; o0.y += a.y; o0.z += a.z; o0.w += a.w;
        o1.x += b.x; o1.y += b.y; o1.z += b.z; o1.w += b.w;
    }
    float4 b0 = *(const float4*)(db + (size_t)e0 * H_DIM + h);
    float4 b1 = *(const float4*)(db + (size_t)e1 * H_DIM + h);
    float4 r;
    r.x = w0 * (o0.x + b0.x) + w1 * (o1.x + b1.x);
    r.y = w0 * (o0.y + b0.y) + w1 * (o1.y + b1.y);
    r.z = w0 * (o0.z + b0.z) + w1 * (o1.z + b1.z);
    r.w = w0 * (o0.w + b0.w) + w1 * (o1.w + b1.w);
    *(float4*)(out + (size_t)t * H_DIM + h) = r;
}

extern "C" void kernel_launch(void* const* d_in, const int* in_sizes, int n_in,
                              void* d_out, int out_size, void* d_ws, size_t ws_size,
                              hipStream_t stream) {
    const float* x     = (const float*)d_in[0];
    const float* rw    = (const float*)d_in[1];
    const float* rb    = (const float*)d_in[2];
    const float* gup   = (const float*)d_in[3];
    const float* gup_b = (const float*)d_in[4];
    const float* dw    = (const float*)d_in[5];
    const float* db    = (const float*)d_in[6];
    float* out    = (float*)d_out;
    float* scores = out + (size_t)T_TOK * H_DIM;

    char* ws = (char*)d_ws;
    int*   counts   = (int*)(ws + WS_COUNTS);
    int*   offsets  = (int*)(ws + WS_OFFSETS);
    int*   tok_e    = (int*)(ws + WS_TOKE);
    int*   tok_p    = (int*)(ws + WS_TOKP);
    float* tok_w    = (float*)(ws + WS_TOKW);
    int*   tok_g    = (int*)(ws + WS_TOKG);
    int*   slot_tok = (int*)(ws + WS_SLOTTOK);
    u16*   xg       = (u16*)(ws + WS_XG);
    u16*   gated    = (u16*)(ws + WS_GATED);
    float* outws    = (float*)(ws + WS_OUT);

    k_zero<<<1, 64, 0, stream>>>(counts);
    k_router<<<T_TOK, 64, 0, stream>>>(x, rw, rb, scores, counts, tok_e, tok_p, tok_w);
    k_offsets<<<1, 64, 0, stream>>>(counts, offsets);
    k_build<<<(2*T_TOK + 255)/256, 256, 0, stream>>>(tok_e, tok_p, offsets, tok_g, slot_tok);
    k_gather<<<2*T_TOK, 256, 0, stream>>>(x, slot_tok, xg);
    dim3 g2(M_DIM/64, 8, E_NUM);
    k_gateup<<<g2, 512, 0, stream>>>(xg, gup, gup_b, counts, offsets, gated);
    dim3 g3(16 * KSPL, 8, E_NUM);
    k_down<<<g3, 512, 0, stream>>>(gated, dw, counts, offsets, outws);
    k_final<<<T_TOK, 256, 0, stream>>>(outws, db, tok_e, tok_g, tok_w, out);
}